// Round 13
// baseline (259.731 us; speedup 1.0000x reference)
//
#include <hip/hip_runtime.h>
#include <hip/hip_bf16.h>

#define BN 8192
#define DIM 512
#define NB  64            // BN / 128 block-rows
#define NTILES 2080       // NB*(NB+1)/2 upper-triangle tiles
#define EPSF 1e-8f

using v8i   = __attribute__((ext_vector_type(8))) int;
using v4i   = __attribute__((ext_vector_type(4))) int;
using f32x4 = __attribute__((ext_vector_type(4))) float;

// Async global->LDS, 16 B per lane, dest = uniform base + lane*16.
__device__ __forceinline__ void async_copy16(const void* g, void* l) {
    __builtin_amdgcn_global_load_lds(
        (const __attribute__((address_space(1))) void*)g,
        (__attribute__((address_space(3))) void*)l,
        16, 0, 0);
}

// One wave per row: L2-normalize, x4 pre-scale, fp8 e4m3. Block 0 zeroes
// out[0] and the completion counter (kernel boundary = device release, so
// gemm sees them).
__global__ __launch_bounds__(256) void normalize_kernel(
        const float* __restrict__ emb, unsigned char* __restrict__ E,
        float* __restrict__ out, int* __restrict__ done) {
    if (blockIdx.x == 0 && threadIdx.x == 0) { out[0] = 0.f; done[0] = 0; }
    int lane = threadIdx.x & 63;
    int row  = blockIdx.x * 4 + (threadIdx.x >> 6);
    const float4* src = (const float4*)(emb + (size_t)row * DIM);
    float4 a = src[lane];
    float4 b = src[lane + 64];
    float ss = a.x*a.x + a.y*a.y + a.z*a.z + a.w*a.w
             + b.x*b.x + b.y*b.y + b.z*b.z + b.w*b.w;
    #pragma unroll
    for (int m = 1; m < 64; m <<= 1) ss += __shfl_xor(ss, m, 64);
    float s4 = 4.0f / fmaxf(sqrtf(ss), 1e-12f);
    int pa = __builtin_amdgcn_cvt_pk_fp8_f32(a.x*s4, a.y*s4, 0, false);
    pa     = __builtin_amdgcn_cvt_pk_fp8_f32(a.z*s4, a.w*s4, pa, true);
    int pb = __builtin_amdgcn_cvt_pk_fp8_f32(b.x*s4, b.y*s4, 0, false);
    pb     = __builtin_amdgcn_cvt_pk_fp8_f32(b.z*s4, b.w*s4, pb, true);
    unsigned char* rowp = E + (size_t)row * DIM;
    ((unsigned*)rowp)[lane]         = (unsigned)pa;
    ((unsigned*)(rowp + 256))[lane] = (unsigned)pb;
}

// Upper-triangle 128x128 tiles. R11 core (A-slab staged in LDS as two BK=256
// chunks, XOR-swizzled; B direct global->VGPR with register double-buffer;
// fp8 MX MFMA 16x16x128) with two additions:
//  (1) XCD-banded schedule: block-row pairs (p, 63-p) have exactly 65 tiles;
//      XCD x (blockIdx%8 round-robin heuristic) owns pairs p==x (mod 8), so
//      each XCD's A-working-set is 8 slabs = 512 KB (L2-resident) instead of
//      random all-to-all against the 4 MB E (= one XCD L2). Perf-only.
//  (2) Fused finalize: completion counter; last 32 finishers each reduce one
//      256-row shard (device-scope fences for cross-XCD visibility).
__global__ __launch_bounds__(256) void gemm_epi_kernel(
        const unsigned char* __restrict__ E, const int* __restrict__ labels,
        float* __restrict__ P, float* __restrict__ N,
        float* __restrict__ out, int* __restrict__ done) {
    __shared__ __attribute__((aligned(16))) unsigned char smem[45056];
    __shared__ int labI[128];
    __shared__ int labJ[128];
    __shared__ int s_old;
    __shared__ float wsum[4];

    // --- XCD-banded triangular decode ---
    int t   = blockIdx.x;
    int xcd = t & 7;
    int j   = t >> 3;             // 0..259
    int p   = xcd + 8 * (j / 65); // pair id 0..31
    int u   = j % 65;             // 0..64
    int n0  = 64 - p;             // tiles in row p
    int bi, bj;
    if (u < n0) { bi = p;      bj = p + u; }
    else        { bi = 63 - p; bj = 63 - p + (u - n0); }
    const bool diag = (bi == bj);
    const int i0 = bi * 128;
    const int j0 = bj * 128;

    const int tid  = threadIdx.x;
    const int wave = tid >> 6;
    const int lane = tid & 63;
    const int quad = lane >> 4;
    const int lrow = lane & 15;
    const int i_w  = (wave >> 1) * 64;
    const int j_w  = (wave & 1) * 64;

    if (tid < 128)       labI[tid]       = labels[i0 + tid];
    else                 labJ[tid - 128] = labels[j0 + tid - 128];

    unsigned char* As = smem;
    float2* rowBuf = (float2*)smem;               // [2][128][17]
    float2* colBuf = (float2*)(smem + 34816);     // [2][128][5]
    const int vR = wave & 1;
    const int vC = wave >> 1;

    f32x4 acc[4][4];
    #pragma unroll
    for (int a = 0; a < 4; ++a)
        #pragma unroll
        for (int b = 0; b < 4; ++b)
            acc[a][b] = (f32x4){0.f, 0.f, 0.f, 0.f};

    const v4i* bptr[4];
    #pragma unroll
    for (int tj = 0; tj < 4; ++tj)
        bptr[tj] = (const v4i*)(E +
            (size_t)(j0 + j_w + tj * 16 + lrow) * DIM + quad * 32);

    v8i bf[2][4];
    #pragma unroll
    for (int tj = 0; tj < 4; ++tj) {      // prefetch B for k=0
        ((v4i*)&bf[0][tj])[0] = bptr[tj][0];
        ((v4i*)&bf[0][tj])[1] = bptr[tj][1];
    }

    // Two BK=256 A-chunks. Stage: wave rows [w*32,w*32+32), 8 instrs x 4 rows;
    // lane l: row base+(l>>4), LDS chunk p=l&15 holds global chunk p^(row&7).
    #pragma unroll
    for (int c = 0; c < 2; ++c) {
        if (c) __syncthreads();           // chunk0 ds_reads done
        #pragma unroll
        for (int h = 0; h < 8; ++h) {
            int base = wave * 32 + h * 4;
            int rowg = base + (lane >> 4);
            int g    = (lane & 15) ^ (rowg & 7);
            async_copy16(E + (size_t)(i0 + rowg) * DIM + c * 256 + g * 16,
                         As + (size_t)base * 256);
        }
        __syncthreads();                  // vmcnt drain: chunk ready

        #pragma unroll
        for (int k2 = 0; k2 < 2; ++k2) {
            const int k   = c * 2 + k2;
            const int cur = k & 1, nxt = cur ^ 1;
            v8i af[4];
            #pragma unroll
            for (int ti = 0; ti < 4; ++ti) {
                int r  = i_w + ti * 16 + lrow;
                const v4i* rp = (const v4i*)(As + (size_t)r * 256);
                int sw = r & 7;
                ((v4i*)&af[ti])[0] = rp[(k2 * 8 + quad * 2) ^ sw];
                ((v4i*)&af[ti])[1] = rp[(k2 * 8 + quad * 2 + 1) ^ sw];
            }
            if (k < 3) {                  // prefetch next k's B
                #pragma unroll
                for (int tj = 0; tj < 4; ++tj) {
                    ((v4i*)&bf[nxt][tj])[0] = bptr[tj][(k + 1) * 8];
                    ((v4i*)&bf[nxt][tj])[1] = bptr[tj][(k + 1) * 8 + 1];
                }
            }
            #pragma unroll
            for (int ti = 0; ti < 4; ++ti)
                #pragma unroll
                for (int tj = 0; tj < 4; ++tj)
                    acc[ti][tj] =
                        __builtin_amdgcn_mfma_scale_f32_16x16x128_f8f6f4(
                            af[ti], bf[cur][tj], acc[ti][tj],
                            0, 0,                 // fp8 e4m3 / e4m3
                            0, 0x7F7F7F7F,        // A scale = 1.0
                            0, 0x7F7F7F7F);       // B scale = 1.0
        }
    }
    __syncthreads();      // As dead -> reduction buffers writable

    // Epilogue. C/D: col = lane&15, row = quad*4 + reg. acc = 16*S.
    float psC[4] = {0.f, 0.f, 0.f, 0.f};
    float nsC[4] = {0.f, 0.f, 0.f, 0.f};
    #pragma unroll
    for (int ti = 0; ti < 4; ++ti) {
        #pragma unroll
        for (int reg = 0; reg < 4; ++reg) {
            int irow = i_w + ti * 16 + quad * 4 + reg;
            int li   = labI[irow];
            int gi   = i0 + irow;
            float ps = 0.f, ns = 0.f;
            #pragma unroll
            for (int tj = 0; tj < 4; ++tj) {
                int jcol = j_w + tj * 16 + lrow;
                int lj   = labJ[jcol];
                int gj   = j0 + jcol;
                float w  = __expf(fmaf(acc[ti][tj][reg], 0.0625f, -1.0f));
                bool same = (li == lj);
                float wp = (same && (gi != gj)) ? w : 0.f;
                float wn = same ? 0.f : w;
                ps += wp;  ns += wn;
                psC[tj] += wp;  nsC[tj] += wn;
            }
            rowBuf[(size_t)(vR * 128 + irow) * 17 + lrow] = (float2){ps, ns};
        }
    }
    #pragma unroll
    for (int tj = 0; tj < 4; ++tj) {
        int jcol = j_w + tj * 16 + lrow;
        colBuf[(size_t)(vC * 128 + jcol) * 5 + quad] = (float2){psC[tj], nsC[tj]};
    }
    __syncthreads();

    if (tid < 128) {
        const float2* a = rowBuf + (size_t)tid * 17;
        const float2* b = rowBuf + (size_t)(128 + tid) * 17;
        float sp = 0.f, sn = 0.f;
        #pragma unroll
        for (int u2 = 0; u2 < 16; ++u2) {
            sp += a[u2].x + b[u2].x;
            sn += a[u2].y + b[u2].y;
        }
        P[(size_t)bj * BN + i0 + tid] = sp;
        N[(size_t)bj * BN + i0 + tid] = sn;
    } else if (!diag) {
        int c2 = tid - 128;
        const float2* a = colBuf + (size_t)c2 * 5;
        const float2* b = colBuf + (size_t)(128 + c2) * 5;
        float sp = 0.f, sn = 0.f;
        #pragma unroll
        for (int u2 = 0; u2 < 4; ++u2) {
            sp += a[u2].x + b[u2].x;
            sn += a[u2].y + b[u2].y;
        }
        P[(size_t)bi * BN + j0 + c2] = sp;
        N[(size_t)bi * BN + j0 + c2] = sn;
    }

    // --- fused finalize: last 32 finishers reduce one shard each ---
    __threadfence();                         // release P/N (cross-XCD)
    if (tid == 0) s_old = atomicAdd(done, 1);
    __syncthreads();                         // also: rowBuf/colBuf reads done
    int old = s_old;
    if (old < NTILES - 32) return;
    int shard = old - (NTILES - 32);         // 0..31

    if (tid == 0) {
        while (__hip_atomic_load(done, __ATOMIC_ACQUIRE,
                                 __HIP_MEMORY_SCOPE_AGENT) < NTILES)
            __builtin_amdgcn_s_sleep(2);
    }
    __syncthreads();
    __threadfence();                         // acquire P/N (cross-XCD)

    int* cnt = (int*)smem;                   // smem reuse (post-barrier)
    if (tid < 128) cnt[tid] = 0;
    __syncthreads();
    for (int i = tid; i < BN; i += 256) atomicAdd(&cnt[labels[i]], 1);
    __syncthreads();

    int i = shard * 256 + tid;
    float pp = 0.f, nn = 0.f;
    #pragma unroll 8
    for (int c = 0; c < NB; ++c) {
        pp += P[(size_t)c * BN + i];
        nn += N[(size_t)c * BN + i];
    }
    int   cl = cnt[labels[i]];
    float pm = pp / fmaxf((float)(cl - 1), 1.0f);
    float nm = nn / fmaxf((float)(BN - cl), 1.0f);
    float v  = ((cl - 1 > 0) && (BN - cl > 0))
                   ? -logf(pm / (pm + nm + EPSF)) : 0.0f;
    v *= (1.0f / (float)BN);
    #pragma unroll
    for (int m = 1; m < 64; m <<= 1) v += __shfl_xor(v, m, 64);
    if ((tid & 63) == 0) wsum[tid >> 6] = v;
    __syncthreads();
    if (tid == 0)
        atomicAdd(out, wsum[0] + wsum[1] + wsum[2] + wsum[3]);
}

extern "C" void kernel_launch(void* const* d_in, const int* in_sizes, int n_in,
                              void* d_out, int out_size, void* d_ws, size_t ws_size,
                              hipStream_t stream) {
    const float* emb   = (const float*)d_in[0];
    const int* labels  = (const int*)d_in[1];
    float* out         = (float*)d_out;

    // ws layout: E (8 MB reserved; fp8 uses 4) | P (2 MB) | N (2 MB) | done
    unsigned char* E   = (unsigned char*)d_ws;
    float* P           = (float*)((char*)d_ws + (size_t)BN * DIM * 2);
    float* N           = P + (size_t)NB * BN;
    int*   done        = (int*)(N + (size_t)NB * BN);

    normalize_kernel<<<BN / 4, 256, 0, stream>>>(emb, E, out, done);
    gemm_epi_kernel<<<NTILES, 256, 0, stream>>>(E, labels, P, N, out, done);
}

// Round 14
// 135.347 us; speedup vs baseline: 1.9190x; 1.9190x over previous
//
#include <hip/hip_runtime.h>
#include <hip/hip_bf16.h>

#define BN 8192
#define DIM 512
#define NB  64            // BN / 128 block-rows
#define NTILES 2080       // NB*(NB+1)/2 upper-triangle tiles
#define EPSF 1e-8f

using v8i   = __attribute__((ext_vector_type(8))) int;
using v4i   = __attribute__((ext_vector_type(4))) int;
using f32x4 = __attribute__((ext_vector_type(4))) float;

// Async global->LDS, 16 B per lane, dest = uniform base + lane*16.
__device__ __forceinline__ void async_copy16(const void* g, void* l) {
    __builtin_amdgcn_global_load_lds(
        (const __attribute__((address_space(1))) void*)g,
        (__attribute__((address_space(3))) void*)l,
        16, 0, 0);
}

// One wave per row: L2-normalize, x4 pre-scale, fp8 e4m3. Block 0 zeroes
// out[0] and the completion counter (dispatch boundary publishes them).
__global__ __launch_bounds__(256) void normalize_kernel(
        const float* __restrict__ emb, unsigned char* __restrict__ E,
        float* __restrict__ out, int* __restrict__ done) {
    if (blockIdx.x == 0 && threadIdx.x == 0) { out[0] = 0.f; done[0] = 0; }
    int lane = threadIdx.x & 63;
    int row  = blockIdx.x * 4 + (threadIdx.x >> 6);
    const float4* src = (const float4*)(emb + (size_t)row * DIM);
    float4 a = src[lane];
    float4 b = src[lane + 64];
    float ss = a.x*a.x + a.y*a.y + a.z*a.z + a.w*a.w
             + b.x*b.x + b.y*b.y + b.z*b.z + b.w*b.w;
    #pragma unroll
    for (int m = 1; m < 64; m <<= 1) ss += __shfl_xor(ss, m, 64);
    float s4 = 4.0f / fmaxf(sqrtf(ss), 1e-12f);
    int pa = __builtin_amdgcn_cvt_pk_fp8_f32(a.x*s4, a.y*s4, 0, false);
    pa     = __builtin_amdgcn_cvt_pk_fp8_f32(a.z*s4, a.w*s4, pa, true);
    int pb = __builtin_amdgcn_cvt_pk_fp8_f32(b.x*s4, b.y*s4, 0, false);
    pb     = __builtin_amdgcn_cvt_pk_fp8_f32(b.z*s4, b.w*s4, pb, true);
    unsigned char* rowp = E + (size_t)row * DIM;
    ((unsigned*)rowp)[lane]         = (unsigned)pa;
    ((unsigned*)(rowp + 256))[lane] = (unsigned)pb;
}

// Upper-triangle 128x128 tiles, 1D grid (2080), LINEAR triangular decode
// (R13's banding reverted -- it was confounded with the fence poison).
// R11 core: A-slab in LDS as two BK=256 chunks (XOR-swizzled, 45 KB);
// B direct global->VGPR with register double-buffer; fp8 MX MFMA 16x16x128.
// FENCE-FREE fused finalize: P/N finals written as device-scope RELAXED
// atomic stores (coherent at L3; no L2 dirty data -> no writeback/invalidate
// anywhere). __syncthreads' implicit vmcnt(0) drains them; one RELEASE
// fetch_add on done per block; the last 32 increments each finalize one
// 256-row shard reading P/N via relaxed agent atomic loads.
__global__ __launch_bounds__(256) void gemm_epi_kernel(
        const unsigned char* __restrict__ E, const int* __restrict__ labels,
        float* __restrict__ P, float* __restrict__ N,
        float* __restrict__ out, int* __restrict__ done) {
    __shared__ __attribute__((aligned(16))) unsigned char smem[45056];
    __shared__ int labI[128];
    __shared__ int labJ[128];
    __shared__ int s_old;
    __shared__ float wsum[4];

    int t  = blockIdx.x;
    int bi = (int)(64.5f - sqrtf(64.5f * 64.5f - 2.0f * (float)t));
    while (64 * (bi + 1) - ((bi + 1) * bi) / 2 <= t) ++bi;
    while (64 * bi - (bi * (bi - 1)) / 2 > t) --bi;
    int bj = bi + (t - (64 * bi - (bi * (bi - 1)) / 2));
    const bool diag = (bi == bj);
    const int i0 = bi * 128;
    const int j0 = bj * 128;

    const int tid  = threadIdx.x;
    const int wave = tid >> 6;
    const int lane = tid & 63;
    const int quad = lane >> 4;
    const int lrow = lane & 15;
    const int i_w  = (wave >> 1) * 64;
    const int j_w  = (wave & 1) * 64;

    if (tid < 128)       labI[tid]       = labels[i0 + tid];
    else                 labJ[tid - 128] = labels[j0 + tid - 128];

    unsigned char* As = smem;
    float2* rowBuf = (float2*)smem;               // [2][128][17]
    float2* colBuf = (float2*)(smem + 34816);     // [2][128][5]
    const int vR = wave & 1;
    const int vC = wave >> 1;

    f32x4 acc[4][4];
    #pragma unroll
    for (int a = 0; a < 4; ++a)
        #pragma unroll
        for (int b = 0; b < 4; ++b)
            acc[a][b] = (f32x4){0.f, 0.f, 0.f, 0.f};

    const v4i* bptr[4];
    #pragma unroll
    for (int tj = 0; tj < 4; ++tj)
        bptr[tj] = (const v4i*)(E +
            (size_t)(j0 + j_w + tj * 16 + lrow) * DIM + quad * 32);

    v8i bf[2][4];
    #pragma unroll
    for (int tj = 0; tj < 4; ++tj) {      // prefetch B for k=0
        ((v4i*)&bf[0][tj])[0] = bptr[tj][0];
        ((v4i*)&bf[0][tj])[1] = bptr[tj][1];
    }

    // Two BK=256 A-chunks. Stage: wave rows [w*32,w*32+32), 8 instrs x 4 rows;
    // lane l: row base+(l>>4), LDS chunk p=l&15 holds global chunk p^(row&7).
    #pragma unroll
    for (int c = 0; c < 2; ++c) {
        if (c) __syncthreads();           // chunk0 ds_reads done
        #pragma unroll
        for (int h = 0; h < 8; ++h) {
            int base = wave * 32 + h * 4;
            int rowg = base + (lane >> 4);
            int g    = (lane & 15) ^ (rowg & 7);
            async_copy16(E + (size_t)(i0 + rowg) * DIM + c * 256 + g * 16,
                         As + (size_t)base * 256);
        }
        __syncthreads();                  // vmcnt drain: chunk ready

        #pragma unroll
        for (int k2 = 0; k2 < 2; ++k2) {
            const int k   = c * 2 + k2;
            const int cur = k & 1, nxt = cur ^ 1;
            v8i af[4];
            #pragma unroll
            for (int ti = 0; ti < 4; ++ti) {
                int r  = i_w + ti * 16 + lrow;
                const v4i* rp = (const v4i*)(As + (size_t)r * 256);
                int sw = r & 7;
                ((v4i*)&af[ti])[0] = rp[(k2 * 8 + quad * 2) ^ sw];
                ((v4i*)&af[ti])[1] = rp[(k2 * 8 + quad * 2 + 1) ^ sw];
            }
            if (k < 3) {                  // prefetch next k's B
                #pragma unroll
                for (int tj = 0; tj < 4; ++tj) {
                    ((v4i*)&bf[nxt][tj])[0] = bptr[tj][(k + 1) * 8];
                    ((v4i*)&bf[nxt][tj])[1] = bptr[tj][(k + 1) * 8 + 1];
                }
            }
            #pragma unroll
            for (int ti = 0; ti < 4; ++ti)
                #pragma unroll
                for (int tj = 0; tj < 4; ++tj)
                    acc[ti][tj] =
                        __builtin_amdgcn_mfma_scale_f32_16x16x128_f8f6f4(
                            af[ti], bf[cur][tj], acc[ti][tj],
                            0, 0,                 // fp8 e4m3 / e4m3
                            0, 0x7F7F7F7F,        // A scale = 1.0
                            0, 0x7F7F7F7F);       // B scale = 1.0
        }
    }
    __syncthreads();      // As dead -> reduction buffers writable

    // Epilogue. C/D: col = lane&15, row = quad*4 + reg. acc = 16*S.
    float psC[4] = {0.f, 0.f, 0.f, 0.f};
    float nsC[4] = {0.f, 0.f, 0.f, 0.f};
    #pragma unroll
    for (int ti = 0; ti < 4; ++ti) {
        #pragma unroll
        for (int reg = 0; reg < 4; ++reg) {
            int irow = i_w + ti * 16 + quad * 4 + reg;
            int li   = labI[irow];
            int gi   = i0 + irow;
            float ps = 0.f, ns = 0.f;
            #pragma unroll
            for (int tj = 0; tj < 4; ++tj) {
                int jcol = j_w + tj * 16 + lrow;
                int lj   = labJ[jcol];
                int gj   = j0 + jcol;
                float w  = __expf(fmaf(acc[ti][tj][reg], 0.0625f, -1.0f));
                bool same = (li == lj);
                float wp = (same && (gi != gj)) ? w : 0.f;
                float wn = same ? 0.f : w;
                ps += wp;  ns += wn;
                psC[tj] += wp;  nsC[tj] += wn;
            }
            rowBuf[(size_t)(vR * 128 + irow) * 17 + lrow] = (float2){ps, ns};
        }
    }
    #pragma unroll
    for (int tj = 0; tj < 4; ++tj) {
        int jcol = j_w + tj * 16 + lrow;
        colBuf[(size_t)(vC * 128 + jcol) * 5 + quad] = (float2){psC[tj], nsC[tj]};
    }
    __syncthreads();

    if (tid < 128) {
        const float2* a = rowBuf + (size_t)tid * 17;
        const float2* b = rowBuf + (size_t)(128 + tid) * 17;
        float sp = 0.f, sn = 0.f;
        #pragma unroll
        for (int u2 = 0; u2 < 16; ++u2) {
            sp += a[u2].x + b[u2].x;
            sn += a[u2].y + b[u2].y;
        }
        __hip_atomic_store(&P[(size_t)bj * BN + i0 + tid], sp,
                           __ATOMIC_RELAXED, __HIP_MEMORY_SCOPE_AGENT);
        __hip_atomic_store(&N[(size_t)bj * BN + i0 + tid], sn,
                           __ATOMIC_RELAXED, __HIP_MEMORY_SCOPE_AGENT);
    } else if (!diag) {
        int c2 = tid - 128;
        const float2* a = colBuf + (size_t)c2 * 5;
        const float2* b = colBuf + (size_t)(128 + c2) * 5;
        float sp = 0.f, sn = 0.f;
        #pragma unroll
        for (int u2 = 0; u2 < 4; ++u2) {
            sp += a[u2].x + b[u2].x;
            sn += a[u2].y + b[u2].y;
        }
        __hip_atomic_store(&P[(size_t)bi * BN + j0 + c2], sp,
                           __ATOMIC_RELAXED, __HIP_MEMORY_SCOPE_AGENT);
        __hip_atomic_store(&N[(size_t)bi * BN + j0 + c2], sn,
                           __ATOMIC_RELAXED, __HIP_MEMORY_SCOPE_AGENT);
    }

    // Fence-free completion protocol: barrier's implicit vmcnt(0) drains the
    // atomic stores to the coherence point before tid0 increments.
    __syncthreads();
    if (tid == 0)
        s_old = __hip_atomic_fetch_add(done, 1, __ATOMIC_RELEASE,
                                       __HIP_MEMORY_SCOPE_AGENT);
    __syncthreads();
    int old = s_old;
    if (old < NTILES - 32) return;
    int shard = old - (NTILES - 32);          // 0..31

    if (tid == 0) {
        while (__hip_atomic_load(done, __ATOMIC_RELAXED,
                                 __HIP_MEMORY_SCOPE_AGENT) < NTILES)
            __builtin_amdgcn_s_sleep(8);
    }
    __syncthreads();

    int* cnt = (int*)smem;                    // smem reuse (post-barrier)
    if (tid < 128) cnt[tid] = 0;
    __syncthreads();
    for (int i = tid; i < BN; i += 256) atomicAdd(&cnt[labels[i]], 1);
    __syncthreads();

    int i = shard * 256 + tid;
    float pp = 0.f, nn = 0.f;
    #pragma unroll 8
    for (int c = 0; c < NB; ++c) {
        pp += __hip_atomic_load(&P[(size_t)c * BN + i], __ATOMIC_RELAXED,
                                __HIP_MEMORY_SCOPE_AGENT);
        nn += __hip_atomic_load(&N[(size_t)c * BN + i], __ATOMIC_RELAXED,
                                __HIP_MEMORY_SCOPE_AGENT);
    }
    int   cl = cnt[labels[i]];
    float pm = pp / fmaxf((float)(cl - 1), 1.0f);
    float nm = nn / fmaxf((float)(BN - cl), 1.0f);
    float v  = ((cl - 1 > 0) && (BN - cl > 0))
                   ? -logf(pm / (pm + nm + EPSF)) : 0.0f;
    v *= (1.0f / (float)BN);
    #pragma unroll
    for (int m = 1; m < 64; m <<= 1) v += __shfl_xor(v, m, 64);
    if ((tid & 63) == 0) wsum[tid >> 6] = v;
    __syncthreads();
    if (tid == 0)
        atomicAdd(out, wsum[0] + wsum[1] + wsum[2] + wsum[3]);
}

extern "C" void kernel_launch(void* const* d_in, const int* in_sizes, int n_in,
                              void* d_out, int out_size, void* d_ws, size_t ws_size,
                              hipStream_t stream) {
    const float* emb   = (const float*)d_in[0];
    const int* labels  = (const int*)d_in[1];
    float* out         = (float*)d_out;

    // ws layout: E (8 MB reserved; fp8 uses 4) | P (2 MB) | N (2 MB) | done
    unsigned char* E   = (unsigned char*)d_ws;
    float* P           = (float*)((char*)d_ws + (size_t)BN * DIM * 2);
    float* N           = P + (size_t)NB * BN;
    int*   done        = (int*)(N + (size_t)NB * BN);

    normalize_kernel<<<BN / 4, 256, 0, stream>>>(emb, E, out, done);
    gemm_epi_kernel<<<NTILES, 256, 0, stream>>>(E, labels, P, N, out, done);
}